// Round 10
// baseline (324.972 us; speedup 1.0000x reference)
//
#include <hip/hip_runtime.h>
#include <hip/hip_bf16.h>

#define NNODES 100000
#define NEDGES 1600000
#define NBUCK 391           // fine buckets of 256 nodes (dst>>8)
#define BCAP 4800           // slack capacity per bucket (mean 4092, +11 sigma)
#define SPLIT_TILE 4096
#define NSPLIT ((NEDGES + SPLIT_TILE - 1) / SPLIT_TILE)  // 391
#define NTILES (NNODES / 16) // 6250 dense tiles, exact

typedef short short8 __attribute__((ext_vector_type(8)));
typedef unsigned short ushx8 __attribute__((ext_vector_type(8)));
typedef float floatx4 __attribute__((ext_vector_type(4)));

// f32 -> bf16 RNE
__device__ __forceinline__ unsigned short f2b(float f) {
    unsigned u = __float_as_uint(f);
    u += 0x7fffu + ((u >> 16) & 1u);
    return (unsigned short)(u >> 16);
}

__device__ __forceinline__ void acc8(float* a, ushx8 u) {
#pragma unroll
    for (int i = 0; i < 8; ++i)
        a[i] += __uint_as_float((unsigned)u[i] << 16);
}

__device__ __forceinline__ void acc8s(float* a, ushx8 u, float s) {
#pragma unroll
    for (int i = 0; i < 8; ++i)
        a[i] = fmaf(s, __uint_as_float((unsigned)u[i] << 16), a[i]);
}

// ---------------- single-pass split: 391 fine buckets by dst>>8 ----------------
// packed u32 = (src << 8) | (dst & 255)   (src < 2^17); dst stashed in LDS
__global__ __launch_bounds__(256) void split_kernel(
    const int* __restrict__ dst, const int* __restrict__ src,
    int* __restrict__ gcur, unsigned* __restrict__ fpairs) {
    __shared__ int lhist[NBUCK];
    __shared__ int lstart[NBUCK];
    __shared__ int ldst[SPLIT_TILE];
    int t = threadIdx.x;
    for (int i = t; i < NBUCK; i += 256) lhist[i] = 0;
    __syncthreads();
    int base = blockIdx.x * SPLIT_TILE;
    int n = min(SPLIT_TILE, NEDGES - base);
    for (int i = t; i < n; i += 256) {
        int d = dst[base + i];
        ldst[i] = d;
        atomicAdd(&lhist[d >> 8], 1);
    }
    __syncthreads();
    for (int i = t; i < NBUCK; i += 256) {
        int c = lhist[i];
        lstart[i] = (c > 0) ? atomicAdd(&gcur[i], c) : 0;
        lhist[i] = 0;  // reuse as local cursor
    }
    __syncthreads();
    for (int i = t; i < n; i += 256) {
        int d = ldst[i];
        int s = src[base + i];
        int k = d >> 8;
        int pos = lstart[k] + atomicAdd(&lhist[k], 1);
        fpairs[(size_t)k * BCAP + pos] = ((unsigned)s << 8) | (unsigned)(d & 255);
    }
}

// ---------------- finalize: inline bucket scan + per-bucket CSR + dinv ----------------
// fpairs read ONCE into LDS stash; histogram during load; scatter from LDS.
__global__ __launch_bounds__(256) void finalize_kernel(
    const unsigned* __restrict__ fpairs, const int* __restrict__ gcur2,
    int* __restrict__ col, int* __restrict__ deg, int* __restrict__ rowoff,
    float* __restrict__ dinv) {
    __shared__ unsigned stash[BCAP];   // 19.2 KB
    __shared__ int ldeg[256];
    __shared__ int lcur[256];
    __shared__ int lsc[256];
    __shared__ int bb[NBUCK + 1];
    int k = blockIdx.x;
    int t = threadIdx.x;
    // inline exclusive scan of all 391 bucket counts (redundant per block, ~1us)
    int a2 = (2 * t < NBUCK) ? gcur2[2 * t] : 0;
    int b2v = (2 * t + 1 < NBUCK) ? gcur2[2 * t + 1] : 0;
    int ts = a2 + b2v;
    lsc[t] = ts;
    __syncthreads();
    for (int s = 1; s < 256; s <<= 1) {
        int v = (t >= s) ? lsc[t - s] : 0;
        __syncthreads();
        lsc[t] += v;
        __syncthreads();
    }
    int excl2 = lsc[t] - ts;
    if (2 * t < NBUCK) bb[2 * t] = excl2;
    if (2 * t + 1 < NBUCK) bb[2 * t + 1] = excl2 + a2;
    ldeg[t] = 0;
    __syncthreads();
    int node0 = k << 8;
    int ncount = min(256, NNODES - node0);
    int base = bb[k];
    int count = gcur2[k];
    const unsigned* pb = fpairs + (size_t)k * BCAP;
    for (int i = t; i < count; i += 256) {
        unsigned p = pb[i];
        stash[i] = p;
        atomicAdd(&ldeg[p & 255], 1);
    }
    __syncthreads();
    int a = ldeg[t];
    lsc[t] = a;
    __syncthreads();
    for (int s = 1; s < 256; s <<= 1) {
        int v = (t >= s) ? lsc[t - s] : 0;
        __syncthreads();
        lsc[t] += v;
        __syncthreads();
    }
    int excl = lsc[t] - a;
    lcur[t] = base + excl;
    if (t < ncount) {
        int n0 = node0 + t;
        rowoff[n0] = base + excl;
        deg[n0] = a;
        dinv[n0] = (a > 0) ? rsqrtf((float)a) : 0.0f;
    }
    __syncthreads();
    for (int i = t; i < count; i += 256) {
        unsigned p = stash[i];
        int dl = (int)(p & 255u);
        int s = (int)(p >> 8);
        int pos = atomicAdd(&lcur[dl], 1);
        col[pos] = s;
    }
}

// ---------------- g0b = bf16(dinv * x), full-width streaming ----------------
__global__ __launch_bounds__(256) void g0_kernel(
    const float* __restrict__ x, const float* __restrict__ dinv,
    unsigned short* __restrict__ g0b) {
    int t = blockIdx.x * 256 + threadIdx.x;   // one float4 per thread
    if (t < NNODES * 16) {
        float di = dinv[t >> 4];
        float4 v = ((const float4*)x)[t];
        ushort4 u;
        u.x = f2b(di * v.x); u.y = f2b(di * v.y);
        u.z = f2b(di * v.z); u.w = f2b(di * v.w);
        ((ushort4*)g0b)[t] = u;
    }
}

// ---------------- kprop/agg gather: one node per wave, 8 groups x 8 lanes x 16B ----------------
// MODE 0: h1b = bf16(x + dinv_i*sum(g0b))            (residual = f32 x; vin pre-scaled)
// MODE 1: h2b = bf16(h1b + dinv_i*sum(dinv_c*h1b))   (per-edge dinv; residual = bf16 h1b)
// MODE 2: aggb = bf16(sum/degm)
template <int MODE>
__global__ __launch_bounds__(256) void gatherw_kernel(
    const unsigned short* __restrict__ vin, const float* __restrict__ hinf,
    const unsigned short* __restrict__ hinb,
    unsigned short* __restrict__ out0,
    const int* __restrict__ rowoff, const int* __restrict__ deg,
    const int* __restrict__ col, const float* __restrict__ dinv) {
    int node = blockIdx.x * 4 + (threadIdx.x >> 6);  // 25000*4 == 100000 exactly
    int lane = threadIdx.x & 63;
    int sub = lane & 7;
    int g = lane >> 3;
    int beg = rowoff[node];
    int dg = deg[node];
    int end = beg + dg;
    float af[8] = {0.f, 0.f, 0.f, 0.f, 0.f, 0.f, 0.f, 0.f};
    float bf[8] = {0.f, 0.f, 0.f, 0.f, 0.f, 0.f, 0.f, 0.f};
    int e = beg + g;
    for (; e + 8 < end; e += 16) {
        int c0 = col[e];
        int c1 = col[e + 8];
        ushx8 u0 = *(const ushx8*)(vin + (size_t)c0 * 64 + sub * 8);
        ushx8 u1 = *(const ushx8*)(vin + (size_t)c1 * 64 + sub * 8);
        if (MODE == 1) {
            float d0 = dinv[c0];
            float d1 = dinv[c1];
            acc8s(af, u0, d0);
            acc8s(bf, u1, d1);
        } else {
            acc8(af, u0);
            acc8(bf, u1);
        }
    }
    if (e < end) {
        int c0 = col[e];
        ushx8 u0 = *(const ushx8*)(vin + (size_t)c0 * 64 + sub * 8);
        if (MODE == 1) {
            float d0 = dinv[c0];
            acc8s(af, u0, d0);
        } else {
            acc8(af, u0);
        }
    }
#pragma unroll
    for (int i = 0; i < 8; ++i) {
        float v = af[i] + bf[i];
        v += __shfl_xor(v, 8);
        v += __shfl_xor(v, 16);
        v += __shfl_xor(v, 32);
        af[i] = v;
    }
    if (lane < 8) {
        size_t off = (size_t)node * 64 + lane * 8;
        ushx8 uh;
        if (MODE <= 1) {
            float di = dinv[node];
            float hv[8];
            if (MODE == 0) {
                float4 h0 = *(const float4*)(hinf + off);
                float4 h1 = *(const float4*)(hinf + off + 4);
                hv[0] = h0.x; hv[1] = h0.y; hv[2] = h0.z; hv[3] = h0.w;
                hv[4] = h1.x; hv[5] = h1.y; hv[6] = h1.z; hv[7] = h1.w;
            } else {
                ushx8 u = *(const ushx8*)(hinb + off);
#pragma unroll
                for (int i = 0; i < 8; ++i) hv[i] = __uint_as_float((unsigned)u[i] << 16);
            }
#pragma unroll
            for (int i = 0; i < 8; ++i) uh[i] = f2b(hv[i] + di * af[i]);
        } else {
            float r = 1.0f / (float)(dg > 0 ? dg : 1);
#pragma unroll
            for (int i = 0; i < 8; ++i) uh[i] = f2b(af[i] * r);
        }
        *(ushx8*)(out0 + off) = uh;
    }
}

// ---------------- dense1 (MFMA): h3 = selu([agg|h2] @ [W2l;W2r] + b2), bf16 out ----------------
__global__ __launch_bounds__(256) void dense1_mfma(
    const unsigned short* __restrict__ aggb, const unsigned short* __restrict__ hb,
    unsigned short* __restrict__ h3b,
    const float* __restrict__ W2l, const float* __restrict__ W2r,
    const float* __restrict__ b2) {
    __shared__ unsigned short Wt[64 * 144];
    int t = threadIdx.x;
    // vectorized staging: 2048 float4s over [W2l | W2r], transpose to Wt[j][k]
    for (int idx = t; idx < 2048; idx += 256) {
        int basef = idx * 4;
        float4 v;
        int k, j;
        if (basef < 4096) {
            v = ((const float4*)W2l)[idx];
            k = basef >> 6; j = basef & 63;
        } else {
            v = ((const float4*)W2r)[idx - 1024];
            int bf2 = basef - 4096;
            k = 64 + (bf2 >> 6); j = bf2 & 63;
        }
        Wt[j * 144 + k]       = f2b(v.x);
        Wt[(j + 1) * 144 + k] = f2b(v.y);
        Wt[(j + 2) * 144 + k] = f2b(v.z);
        Wt[(j + 3) * 144 + k] = f2b(v.w);
    }
    __syncthreads();
    int wib = t >> 6, lane = t & 63;
    int tile = blockIdx.x * 4 + wib;
    if (tile >= NTILES) return;
    int node0 = tile * 16;
    int jj = lane & 15, kg = lane >> 4;
    short8 bfrag[4][4];
#pragma unroll
    for (int nt = 0; nt < 4; ++nt)
#pragma unroll
        for (int s = 0; s < 4; ++s)
            bfrag[nt][s] = *(const short8*)&Wt[(nt * 16 + jj) * 144 + s * 32 + kg * 8];
    int arow = node0 + jj;
    const unsigned short* ap = aggb + (size_t)arow * 64 + kg * 8;
    const unsigned short* hp = hb + (size_t)arow * 64 + kg * 8;
    short8 afrag[4];
    afrag[0] = *(const short8*)ap;
    afrag[1] = *(const short8*)(ap + 32);
    afrag[2] = *(const short8*)hp;
    afrag[3] = *(const short8*)(hp + 32);
    const float lam = 1.0507009873554804934193349852946f;
    const float alp = 1.6732632423543772848170429916717f;
#pragma unroll
    for (int nt = 0; nt < 4; ++nt) {
        floatx4 acc = {0.f, 0.f, 0.f, 0.f};
#pragma unroll
        for (int s = 0; s < 4; ++s)
            acc = __builtin_amdgcn_mfma_f32_16x16x32_bf16(afrag[s], bfrag[nt][s], acc, 0, 0, 0);
        float bias = b2[nt * 16 + jj];
#pragma unroll
        for (int r = 0; r < 4; ++r) {
            float v = acc[r] + bias;
            float o = (v > 0.0f) ? lam * v : lam * alp * expm1f(v);
            int node = node0 + kg * 4 + r;
            h3b[(size_t)node * 64 + nt * 16 + jj] = f2b(o);
        }
    }
}

// ---------------- dense2 (MFMA) + softmax(16) ----------------
__global__ __launch_bounds__(256) void dense2_mfma(
    const unsigned short* __restrict__ aggb, const unsigned short* __restrict__ hb,
    float* __restrict__ out,
    const float* __restrict__ W3l, const float* __restrict__ W3r,
    const float* __restrict__ b3) {
    __shared__ unsigned short Wt[16 * 144];
    int t = threadIdx.x;
    // vectorized staging: 512 float4s over [W3l | W3r], transpose to Wt[j][k]
    for (int idx = t; idx < 512; idx += 256) {
        int basef = idx * 4;
        float4 v;
        int k, j;
        if (basef < 1024) {
            v = ((const float4*)W3l)[idx];
            k = basef >> 4; j = basef & 15;
        } else {
            v = ((const float4*)W3r)[idx - 256];
            int bf2 = basef - 1024;
            k = 64 + (bf2 >> 4); j = bf2 & 15;
        }
        Wt[j * 144 + k]       = f2b(v.x);
        Wt[(j + 1) * 144 + k] = f2b(v.y);
        Wt[(j + 2) * 144 + k] = f2b(v.z);
        Wt[(j + 3) * 144 + k] = f2b(v.w);
    }
    __syncthreads();
    int wib = t >> 6, lane = t & 63;
    int tile = blockIdx.x * 4 + wib;
    if (tile >= NTILES) return;
    int node0 = tile * 16;
    int jj = lane & 15, kg = lane >> 4;
    short8 bfrag[4];
#pragma unroll
    for (int s = 0; s < 4; ++s)
        bfrag[s] = *(const short8*)&Wt[jj * 144 + s * 32 + kg * 8];
    int arow = node0 + jj;
    const unsigned short* ap = aggb + (size_t)arow * 64 + kg * 8;
    const unsigned short* hp = hb + (size_t)arow * 64 + kg * 8;
    short8 afrag[4];
    afrag[0] = *(const short8*)ap;
    afrag[1] = *(const short8*)(ap + 32);
    afrag[2] = *(const short8*)hp;
    afrag[3] = *(const short8*)(hp + 32);
    floatx4 acc = {0.f, 0.f, 0.f, 0.f};
#pragma unroll
    for (int s = 0; s < 4; ++s)
        acc = __builtin_amdgcn_mfma_f32_16x16x32_bf16(afrag[s], bfrag[s], acc, 0, 0, 0);
    float bias = b3[jj];
#pragma unroll
    for (int r = 0; r < 4; ++r) {
        float v = acc[r] + bias;
        float m = v;
        m = fmaxf(m, __shfl_xor(m, 1));
        m = fmaxf(m, __shfl_xor(m, 2));
        m = fmaxf(m, __shfl_xor(m, 4));
        m = fmaxf(m, __shfl_xor(m, 8));
        float ex = expf(v - m);
        float s2 = ex;
        s2 += __shfl_xor(s2, 1);
        s2 += __shfl_xor(s2, 2);
        s2 += __shfl_xor(s2, 4);
        s2 += __shfl_xor(s2, 8);
        int node = node0 + kg * 4 + r;
        out[(size_t)node * 16 + jj] = ex / s2;
    }
}

extern "C" void kernel_launch(void* const* d_in, const int* in_sizes, int n_in,
                              void* d_out, int out_size, void* d_ws, size_t ws_size,
                              hipStream_t stream) {
    const float* x   = (const float*)d_in[0];
    const int*   ei  = (const int*)d_in[1];
    const float* W2l = (const float*)d_in[2];
    const float* W2r = (const float*)d_in[3];
    const float* b2  = (const float*)d_in[4];
    const float* W3l = (const float*)d_in[5];
    const float* W3r = (const float*)d_in[6];
    const float* b3  = (const float*)d_in[7];
    float* out = (float*)d_out;

    const int* dst = ei;           // edge_index[0]
    const int* src = ei + NEDGES;  // edge_index[1]

    char* ws = (char*)d_ws;
    unsigned short* B0 = (unsigned short*)ws; ws += (size_t)NNODES * 64 * 2;  // g0b -> h2b
    unsigned short* B1 = (unsigned short*)ws; ws += (size_t)NNODES * 64 * 2;  // h1b -> h3b
    unsigned short* B2 = (unsigned short*)ws; ws += (size_t)NNODES * 64 * 2;  // agg1b -> agg2b
    unsigned* fpairs  = (unsigned*)ws; ws += (size_t)NBUCK * BCAP * 4;        // 7.5 MB
    int*      col     = (int*)ws;      ws += (size_t)NEDGES * 4;
    int*      deg     = (int*)ws;      ws += (size_t)NNODES * 4;
    int*      rowoff  = (int*)ws;      ws += (size_t)NNODES * 4;
    float*    dinv    = (float*)ws;    ws += (size_t)NNODES * 4;
    int*      gcur    = (int*)ws;      ws += NBUCK * 4;

    unsigned short* h1b = B1;
    unsigned short* h2b = B0;          // g0b dead after gatherw<0>
    unsigned short* h3b = B1;          // h1b dead after gatherw<1> consumed it

    hipMemsetAsync(gcur, 0, NBUCK * 4, stream);

    split_kernel<<<NSPLIT, 256, 0, stream>>>(dst, src, gcur, fpairs);
    finalize_kernel<<<NBUCK, 256, 0, stream>>>(fpairs, gcur, col, deg, rowoff, dinv);
    g0_kernel<<<(NNODES * 16 + 255) / 256, 256, 0, stream>>>(x, dinv, B0);

    int nblk = NNODES / 4;                 // 25000, exact
    int ndense = (NTILES + 3) / 4;         // 1563
    // KProp step 1: h1b = bf16(x + dinv_i*sum(g0b[c]))
    gatherw_kernel<0><<<nblk, 256, 0, stream>>>(B0, x, nullptr, h1b, rowoff, deg, col, dinv);
    // KProp step 2: h2b = bf16(h1b + dinv_i*sum(dinv_c*h1b[c]))
    gatherw_kernel<1><<<nblk, 256, 0, stream>>>(h1b, nullptr, h1b, h2b, rowoff, deg, col, dinv);
    // SAGE1 aggregate: agg1b = bf16(mean(h2b[neigh]))
    gatherw_kernel<2><<<nblk, 256, 0, stream>>>(h2b, nullptr, nullptr, B2, rowoff, deg, col, dinv);
    // dense1: h3b = bf16(selu(agg1@W2l + h2@W2r + b2))
    dense1_mfma<<<ndense, 256, 0, stream>>>(B2, h2b, h3b, W2l, W2r, b2);
    // SAGE2 aggregate: agg2b = bf16(mean(h3b[neigh]))
    gatherw_kernel<2><<<nblk, 256, 0, stream>>>(h3b, nullptr, nullptr, B2, rowoff, deg, col, dinv);
    // dense2 + softmax
    dense2_mfma<<<ndense, 256, 0, stream>>>(B2, h3b, out, W3l, W3r, b3);
}